// Round 6
// baseline (4405.817 us; speedup 1.0000x reference)
//
#include <hip/hip_runtime.h>

// 32 chained bottleneck blocks on x[16,256,64,64] fp32.
// Phase A: h1_0 = relu(W1_0 x + b1_0)           (reads x once)
// Phase B2 (x16): TWO fused bottleneck steps per dispatch via halo
//   recompute (no inter-block sync needed): stage h1 12x12 (2-halo),
//   step A computed on 10x10 (conv+expand+reduce in LDS, 1.56x inflation),
//   step B on the 8x8 tile. h2 of both steps stored for phaseC.
// Phase C: out = sum_k relu(W3_k h2_k + b3_k)
//
// R12: R5's cooperative grid.sync produced nondeterministic garbage under
// the harness graph capture -> abandoned. Fusion via recompute instead:
// halves the 32 dependent dispatch boundaries (~7us overhead each, the
// dominant phaseB cost per R1/R4 counters) for +28% VALU work. Weight
// LDS reads are 2-address broadcast (32ch/group split). phaseA/phaseC
// identical to R4 measured versions.

#define NN 16
#define HH 64
#define WW 64
#define CIN 256
#define CB 4
#define NBLK 32

// bijective swizzle within 128: spreads stride-4/2 f4 patterns across banks
__device__ __forceinline__ int swzp(int p) { return p ^ ((p >> 3) & 7); }

// ---------------- Phase A: h1_0 = relu(W1_0 . x + b1_0) ------------------
__global__ __launch_bounds__(256) void phaseA(
    const float* __restrict__ x, const float* __restrict__ w1,
    const float* __restrict__ b1, float* __restrict__ h1out) {
  __shared__ float4 w1s[CIN];
  __shared__ float4 part[4][WW];
  int tid = threadIdx.x;
  for (int i = tid; i < CIN * CB; i += 256) {
    int o = i >> 8, c = i & 255;
    ((float*)&w1s[c])[o] = w1[i]; // w1 global layout [o][c]
  }
  __syncthreads();
  int y = blockIdx.x, n = blockIdx.y;
  int chunk = tid >> 6, px = tid & 63;
  int cbase = chunk * 64;
  const float* xp = x + ((n * CIN + cbase) * HH + y) * WW + px;
  float s0 = 0.f, s1 = 0.f, s2 = 0.f, s3 = 0.f;
#pragma unroll 8
  for (int i = 0; i < 64; ++i) {
    float xv = xp[i * HH * WW];
    float4 wv = w1s[cbase + i];
    s0 = fmaf(xv, wv.x, s0);
    s1 = fmaf(xv, wv.y, s1);
    s2 = fmaf(xv, wv.z, s2);
    s3 = fmaf(xv, wv.w, s3);
  }
  part[chunk][px] = make_float4(s0, s1, s2, s3);
  __syncthreads();
  int px2 = tid >> 2, o = tid & 3;
  float v = ((float*)&part[0][px2])[o] + ((float*)&part[1][px2])[o] +
            ((float*)&part[2][px2])[o] + ((float*)&part[3][px2])[o];
  v += b1[o];
  h1out[((n * HH + y) * WW + px2) * CB + o] = fmaxf(v, 0.f);
}

// ---------------- Phase B2: two fused bottleneck steps -------------------
// 8x8 output tile, 256 threads, grid (8,8,16) = 1024 blocks.
// Step A on the 10x10 halo region (recompute), step B on the 8x8 tile.
// Expand: q = tid>>5 owns 32 channels (weight reads 2-addr broadcast),
// pg = tid&31 owns 4 px (A) / 2 px (B). 6 barriers per dispatch.
__global__ __launch_bounds__(256, 4) void phaseB2(
    const float* __restrict__ h1in, float* __restrict__ h1out,
    float* __restrict__ h2outA, float* __restrict__ h2outB,
    const float* __restrict__ w2A, const float* __restrict__ b2A,
    const float* __restrict__ w3A, const float* __restrict__ b3A,
    const float* __restrict__ w1A, const float* __restrict__ b1A, // k+1
    const float* __restrict__ w2B, const float* __restrict__ b2B,
    const float* __restrict__ w3B, const float* __restrict__ b3B,
    const float* __restrict__ w1B, const float* __restrict__ b1B, // k+2
    int compute_next) {
  __shared__ float4 h1t[12][13];  // staged h1, 2-halo          2496 B
  __shared__ float4 wpk[CIN][2];  // [c][0]=w3, [c][1]=w1next^T 8192 B
  __shared__ float4 b3s[64];      //                            1024 B
  __shared__ float h2A[4][112];   // step-A conv out, 10x10     1792 B
  __shared__ float4 h1n[12][13];  // h1_{k+1} region 10x10      2496 B
  __shared__ float h2Bs[4][64];   // step-B conv out            1024 B
  __shared__ float4 comb[8][117]; // expand partials           14976 B
  // total ~31.3 KB -> 4+ blocks/CU

  int tid = threadIdx.x;
  int lane = tid & 63;
  int wvu = __builtin_amdgcn_readfirstlane(tid >> 6); // conv oc
  int q = tid >> 5, pg = tid & 31;                    // expand split
  int x0 = blockIdx.x * 8, y0 = blockIdx.y * 8, n = blockIdx.z;
  int lx = lane & 7, ly = lane >> 3;

  // ---- P0: stage h1 tile (zero halo) + step-A weights ----
  if (tid < 144) {
    int cy = tid / 12, cx = tid % 12;
    int sy = y0 - 2 + cy, sx = x0 - 2 + cx;
    float4 v = make_float4(0.f, 0.f, 0.f, 0.f);
    if (sy >= 0 && sy < HH && sx >= 0 && sx < WW)
      v = *(const float4*)&h1in[((n * HH + sy) * WW + sx) * CB];
    h1t[cy][cx] = v;
  }
  {
    int c = tid;
    wpk[c][0] = *(const float4*)&w3A[c * 4];
    float4 wt;
    wt.x = w1A[c]; wt.y = w1A[256 + c];
    wt.z = w1A[512 + c]; wt.w = w1A[768 + c];
    wpk[c][1] = wt;
    if (tid < 64) b3s[tid] = *(const float4*)&b3A[tid * 4];
  }
  __syncthreads(); // S0

  // ---- P1: conv A on 10x10 region (oc = wave, <=2 px per lane) ----
  {
    const float* w2w = w2A + wvu * 36; // uniform -> s_load
#pragma unroll
    for (int rep = 0; rep < 2; ++rep) {
      int p = lane + rep * 64;
      if (p < 100) {
        int ay = p / 10, ax = p % 10;
        float a0 = b2A[wvu], a1 = 0.f, a2 = 0.f;
#pragma unroll
        for (int dy = 0; dy < 3; ++dy) {
          float4 va = h1t[ay + dy][ax];
          float4 vb = h1t[ay + dy][ax + 1];
          float4 vc = h1t[ay + dy][ax + 2];
          int pp = dy * 3;
          a0 = fmaf(va.x, w2w[pp], a0);
          a0 = fmaf(va.y, w2w[9 + pp], a0);
          a0 = fmaf(va.z, w2w[18 + pp], a0);
          a0 = fmaf(va.w, w2w[27 + pp], a0);
          a1 = fmaf(vb.x, w2w[pp + 1], a1);
          a1 = fmaf(vb.y, w2w[9 + pp + 1], a1);
          a1 = fmaf(vb.z, w2w[18 + pp + 1], a1);
          a1 = fmaf(vb.w, w2w[27 + pp + 1], a1);
          a2 = fmaf(vc.x, w2w[pp + 2], a2);
          a2 = fmaf(vc.y, w2w[9 + pp + 2], a2);
          a2 = fmaf(vc.z, w2w[18 + pp + 2], a2);
          a2 = fmaf(vc.w, w2w[27 + pp + 2], a2);
        }
        h2A[wvu][p] = fmaxf(a0 + a1 + a2, 0.f);
      }
    }
  }
  __syncthreads(); // S1

  // ---- P2: expand A (32ch x 4px per thread) + h2A interior store ----
  {
    float4 h2r[4], tp[4];
#pragma unroll
    for (int j = 0; j < 4; ++j) {
      int p = pg * 4 + j;
      int pc = (p < 100) ? p : 99;
      h2r[j].x = h2A[0][pc]; h2r[j].y = h2A[1][pc];
      h2r[j].z = h2A[2][pc]; h2r[j].w = h2A[3][pc];
      tp[j] = make_float4(0.f, 0.f, 0.f, 0.f);
    }
#pragma unroll
    for (int cc = 0; cc < 32; ++cc) {
      int c = q * 32 + cc;
      float4 w3v = wpk[c][0]; // 2-addr broadcast per wave
      float4 wnv = wpk[c][1];
      float bb = ((const float*)b3s)[c];
#pragma unroll
      for (int j = 0; j < 4; ++j) {
        float u = fmaf(h2r[j].x, w3v.x, bb);
        u = fmaf(h2r[j].y, w3v.y, u);
        u = fmaf(h2r[j].z, w3v.z, u);
        u = fmaf(h2r[j].w, w3v.w, u);
        float v = fmaxf(u, 0.f);
        tp[j].x = fmaf(v, wnv.x, tp[j].x);
        tp[j].y = fmaf(v, wnv.y, tp[j].y);
        tp[j].z = fmaf(v, wnv.z, tp[j].z);
        tp[j].w = fmaf(v, wnv.w, tp[j].w);
      }
    }
#pragma unroll
    for (int j = 0; j < 4; ++j) {
      int p = pg * 4 + j;
      if (p < 100) comb[q][swzp(p)] = tp[j];
    }
    if (tid < 64) { // gather interior h2A -> global (phaseC input, step kA)
      int p = (ly + 1) * 10 + lx + 1;
      float4 h;
      h.x = h2A[0][p]; h.y = h2A[1][p]; h.z = h2A[2][p]; h.w = h2A[3][p];
      *(float4*)&h2outA[((n * HH + y0 + ly) * WW + x0 + lx) * CB] = h;
    }
  }
  __syncthreads(); // S2

  // ---- P3: reduce A -> h1n (10x10, zero outside image) + stage B wts ----
  if (tid < 100) {
    int m = swzp(tid);
    float4 t = comb[0][m];
#pragma unroll
    for (int qq = 1; qq < 8; ++qq) {
      float4 pv = comb[qq][m];
      t.x += pv.x; t.y += pv.y; t.z += pv.z; t.w += pv.w;
    }
    int ay = tid / 10, ax = tid % 10;
    int gy = y0 - 1 + ay, gx = x0 - 1 + ax;
    float4 r;
    r.x = fmaxf(t.x + b1A[0], 0.f);
    r.y = fmaxf(t.y + b1A[1], 0.f);
    r.z = fmaxf(t.z + b1A[2], 0.f);
    r.w = fmaxf(t.w + b1A[3], 0.f);
    if (gy < 0 || gy >= HH || gx < 0 || gx >= WW)
      r = make_float4(0.f, 0.f, 0.f, 0.f); // exact SAME-pad for step B
    h1n[ay][ax] = r;
  }
  {
    int c = tid;
    wpk[c][0] = *(const float4*)&w3B[c * 4];
    float4 wt;
    wt.x = w1B[c]; wt.y = w1B[256 + c];
    wt.z = w1B[512 + c]; wt.w = w1B[768 + c];
    wpk[c][1] = wt;
    if (tid < 64) b3s[tid] = *(const float4*)&b3B[tid * 4];
  }
  __syncthreads(); // S3

  // ---- P4: conv B on 8x8 tile (oc = wave, 1 px per lane) ----
  {
    const float* w2w = w2B + wvu * 36; // uniform -> s_load
    float a0 = b2B[wvu], a1 = 0.f, a2 = 0.f;
#pragma unroll
    for (int dy = 0; dy < 3; ++dy) {
      float4 va = h1n[ly + dy][lx];
      float4 vb = h1n[ly + dy][lx + 1];
      float4 vc = h1n[ly + dy][lx + 2];
      int pp = dy * 3;
      a0 = fmaf(va.x, w2w[pp], a0);
      a0 = fmaf(va.y, w2w[9 + pp], a0);
      a0 = fmaf(va.z, w2w[18 + pp], a0);
      a0 = fmaf(va.w, w2w[27 + pp], a0);
      a1 = fmaf(vb.x, w2w[pp + 1], a1);
      a1 = fmaf(vb.y, w2w[9 + pp + 1], a1);
      a1 = fmaf(vb.z, w2w[18 + pp + 1], a1);
      a1 = fmaf(vb.w, w2w[27 + pp + 1], a1);
      a2 = fmaf(vc.x, w2w[pp + 2], a2);
      a2 = fmaf(vc.y, w2w[9 + pp + 2], a2);
      a2 = fmaf(vc.z, w2w[18 + pp + 2], a2);
      a2 = fmaf(vc.w, w2w[27 + pp + 2], a2);
    }
    h2Bs[wvu][lane] = fmaxf(a0 + a1 + a2, 0.f);
  }
  __syncthreads(); // S4

  // ---- P5: h2B store + expand B (32ch x 2px per thread) ----
  if (tid < 64) {
    float4 h;
    h.x = h2Bs[0][lane]; h.y = h2Bs[1][lane];
    h.z = h2Bs[2][lane]; h.w = h2Bs[3][lane];
    *(float4*)&h2outB[((n * HH + y0 + ly) * WW + x0 + lx) * CB] = h;
  }
  if (compute_next) {
    float4 hb[2], tp[2];
#pragma unroll
    for (int j = 0; j < 2; ++j) {
      int p = pg * 2 + j;
      hb[j].x = h2Bs[0][p]; hb[j].y = h2Bs[1][p];
      hb[j].z = h2Bs[2][p]; hb[j].w = h2Bs[3][p];
      tp[j] = make_float4(0.f, 0.f, 0.f, 0.f);
    }
#pragma unroll
    for (int cc = 0; cc < 32; ++cc) {
      int c = q * 32 + cc;
      float4 w3v = wpk[c][0];
      float4 wnv = wpk[c][1];
      float bb = ((const float*)b3s)[c];
#pragma unroll
      for (int j = 0; j < 2; ++j) {
        float u = fmaf(hb[j].x, w3v.x, bb);
        u = fmaf(hb[j].y, w3v.y, u);
        u = fmaf(hb[j].z, w3v.z, u);
        u = fmaf(hb[j].w, w3v.w, u);
        float v = fmaxf(u, 0.f);
        tp[j].x = fmaf(v, wnv.x, tp[j].x);
        tp[j].y = fmaf(v, wnv.y, tp[j].y);
        tp[j].z = fmaf(v, wnv.z, tp[j].z);
        tp[j].w = fmaf(v, wnv.w, tp[j].w);
      }
    }
#pragma unroll
    for (int j = 0; j < 2; ++j) comb[q][swzp(pg * 2 + j)] = tp[j];
  }
  __syncthreads(); // S5

  if (compute_next && tid < 64) {
    int m = swzp(lane);
    float4 t = comb[0][m];
#pragma unroll
    for (int qq = 1; qq < 8; ++qq) {
      float4 pv = comb[qq][m];
      t.x += pv.x; t.y += pv.y; t.z += pv.z; t.w += pv.w;
    }
    float4 r;
    r.x = fmaxf(t.x + b1B[0], 0.f);
    r.y = fmaxf(t.y + b1B[1], 0.f);
    r.z = fmaxf(t.z + b1B[2], 0.f);
    r.w = fmaxf(t.w + b1B[3], 0.f);
    *(float4*)&h1out[((n * HH + y0 + ly) * WW + x0 + lx) * CB] = r;
  }
}

// ---------------- Phase C: acc = sum_k relu(W3_k h2_k + b3_k) ------------
// (R4 version, measured 115us, VGPR 24, no spill.)
__global__ __launch_bounds__(256, 2) void phaseC(
    const float* __restrict__ h2buf, const float* __restrict__ w3g,
    const float* __restrict__ b3g, float* __restrict__ out) {
  int tid = threadIdx.x;
  int lane = tid & 63;
  int wvu = __builtin_amdgcn_readfirstlane(tid >> 6);
  int bx = blockIdx.x;
  int p0 = (bx >> 1) * 64;
  int cb = (bx & 1) * 128 + wvu * 32;
  int n = blockIdx.y;

  float acc[32];
#pragma unroll
  for (int i = 0; i < 32; ++i) acc[i] = 0.f;

  float4 h = *(const float4*)&h2buf[((0 * NN + n) * 4096 + p0 + lane) * 4];
  for (int k = 0; k < NBLK; ++k) {
    float4 hn = h;
    if (k + 1 < NBLK)
      hn = *(const float4*)&h2buf[(((k + 1) * NN + n) * 4096 + p0 + lane) * 4];
    const float* wrow = w3g + (k * 256 + cb) * 4; // uniform -> s_load
    const float* brow = b3g + k * 256 + cb;       // uniform -> s_load
#pragma unroll
    for (int cc = 0; cc < 32; ++cc) {
      float u = brow[cc];
      u = fmaf(h.x, wrow[cc * 4 + 0], u);
      u = fmaf(h.y, wrow[cc * 4 + 1], u);
      u = fmaf(h.z, wrow[cc * 4 + 2], u);
      u = fmaf(h.w, wrow[cc * 4 + 3], u);
      acc[cc] += fmaxf(u, 0.f);
    }
    h = hn;
  }

#pragma unroll
  for (int cc = 0; cc < 32; ++cc)
    out[(n * CIN + cb + cc) * (HH * WW) + p0 + lane] = acc[cc];
}

extern "C" void kernel_launch(void* const* d_in, const int* in_sizes, int n_in,
                              void* d_out, int out_size, void* d_ws, size_t ws_size,
                              hipStream_t stream) {
  const float* x  = (const float*)d_in[0];
  const float* w1 = (const float*)d_in[1]; // [32][4][256]
  const float* b1 = (const float*)d_in[2]; // [32][4]
  const float* w2 = (const float*)d_in[3]; // [32][4][4][3][3]
  const float* b2 = (const float*)d_in[4]; // [32][4]
  const float* w3 = (const float*)d_in[5]; // [32][256][4]
  const float* b3 = (const float*)d_in[6]; // [32][256]
  float* out = (float*)d_out;
  float* ws = (float*)d_ws;

  const int STATE = NN * HH * WW * CB; // 262144 floats = 1 MiB
  float* h1a = ws;
  float* h1b = ws + STATE;
  float* h2  = ws + 2 * STATE; // 32 MiB -> total 34 MiB (proven footprint)

  phaseA<<<dim3(HH, NN), 256, 0, stream>>>(x, w1, b1, h1a);
  for (int t = 0; t < NBLK / 2; ++t) {
    int kA = 2 * t, kB = 2 * t + 1;
    const float* hin = (t & 1) ? h1b : h1a;
    float* hout = (t & 1) ? h1a : h1b;
    int knA = kA + 1;                       // always <= 31
    int knB = (kB + 1 < NBLK) ? kB + 1 : NBLK - 1; // clamped, unused on last
    phaseB2<<<dim3(8, 8, NN), 256, 0, stream>>>(
        hin, hout, h2 + kA * STATE, h2 + kB * STATE,
        w2 + kA * 144, b2 + kA * CB, w3 + kA * 1024, b3 + kA * 256,
        w1 + knA * 1024, b1 + knA * CB,
        w2 + kB * 144, b2 + kB * CB, w3 + kB * 1024, b3 + kB * 256,
        w1 + knB * 1024, b1 + knB * CB,
        (t < NBLK / 2 - 1) ? 1 : 0);
  }
  phaseC<<<dim3(2 * (HH * WW) / 64, NN), 256, 0, stream>>>(h2, w3, b3, out);
}

// Round 7
// 1402.774 us; speedup vs baseline: 3.1408x; 3.1408x over previous
//
#include <hip/hip_runtime.h>

// 32 chained bottleneck blocks on x[16,256,64,64] fp32.
// Phase A: h1_0 = relu(W1_0 x + b1_0)           (reads x once)
// Phase B2 (x16): TWO fused bottleneck steps per dispatch via halo
//   recompute (no inter-block sync needed): stage h1 12x12 (2-halo),
//   step A computed on 10x10 (conv+expand+reduce in LDS, 1.56x inflation),
//   step B on the 8x8 tile. h2 of both steps stored for phaseC.
// Phase C: out = sum_k relu(W3_k h2_k + b3_k)   (R0 version, 100us proven)
//
// R13: R6's 289us/dispatch was VGPR spill: __launch_bounds__(256,4) caps
// VGPR at 64 on gfx950 (measured R3+R6), fused live set needs ~100 ->
// 820MB scratch traffic/dispatch. RULE: (256,4) only for kernels proven
// <=64 VGPR (R0 phaseC=52, R4 phaseC=24). phaseB2 -> (256,2); phaseC ->
// R0 verbatim.

#define NN 16
#define HH 64
#define WW 64
#define CIN 256
#define CB 4
#define NBLK 32
#define PXT 32  // pixels per phaseC block

// bijective swizzle: spreads stride-4/2 f4 patterns across banks
__device__ __forceinline__ int swzp(int p) { return p ^ ((p >> 3) & 7); }

// ---------------- Phase A: h1_0 = relu(W1_0 . x + b1_0) ------------------
__global__ __launch_bounds__(256) void phaseA(
    const float* __restrict__ x, const float* __restrict__ w1,
    const float* __restrict__ b1, float* __restrict__ h1out) {
  __shared__ float4 w1s[CIN];
  __shared__ float4 part[4][WW];
  int tid = threadIdx.x;
  for (int i = tid; i < CIN * CB; i += 256) {
    int o = i >> 8, c = i & 255;
    ((float*)&w1s[c])[o] = w1[i]; // w1 global layout [o][c]
  }
  __syncthreads();
  int y = blockIdx.x, n = blockIdx.y;
  int chunk = tid >> 6, px = tid & 63;
  int cbase = chunk * 64;
  const float* xp = x + ((n * CIN + cbase) * HH + y) * WW + px;
  float s0 = 0.f, s1 = 0.f, s2 = 0.f, s3 = 0.f;
#pragma unroll 8
  for (int i = 0; i < 64; ++i) {
    float xv = xp[i * HH * WW];
    float4 wv = w1s[cbase + i];
    s0 = fmaf(xv, wv.x, s0);
    s1 = fmaf(xv, wv.y, s1);
    s2 = fmaf(xv, wv.z, s2);
    s3 = fmaf(xv, wv.w, s3);
  }
  part[chunk][px] = make_float4(s0, s1, s2, s3);
  __syncthreads();
  int px2 = tid >> 2, o = tid & 3;
  float v = ((float*)&part[0][px2])[o] + ((float*)&part[1][px2])[o] +
            ((float*)&part[2][px2])[o] + ((float*)&part[3][px2])[o];
  v += b1[o];
  h1out[((n * HH + y) * WW + px2) * CB + o] = fmaxf(v, 0.f);
}

// ---------------- Phase B2: two fused bottleneck steps -------------------
// 8x8 output tile, 256 threads, grid (8,8,16) = 1024 blocks.
// Step A on the 10x10 halo region (recompute), step B on the 8x8 tile.
// Expand: q = tid>>5 owns 32 channels (weight reads 2-addr broadcast),
// pg = tid&31 owns 4 px (A) / 2 px (B). 6 barriers per dispatch.
// (256,2): 128-VGPR cap, no spill; LDS 31.5KB -> 4-5 blocks/CU.
__global__ __launch_bounds__(256, 2) void phaseB2(
    const float* __restrict__ h1in, float* __restrict__ h1out,
    float* __restrict__ h2outA, float* __restrict__ h2outB,
    const float* __restrict__ w2A, const float* __restrict__ b2A,
    const float* __restrict__ w3A, const float* __restrict__ b3A,
    const float* __restrict__ w1A, const float* __restrict__ b1A, // k+1
    const float* __restrict__ w2B, const float* __restrict__ b2B,
    const float* __restrict__ w3B, const float* __restrict__ b3B,
    const float* __restrict__ w1B, const float* __restrict__ b1B, // k+2
    int compute_next) {
  __shared__ float4 h1t[12][13];  // staged h1, 2-halo          2496 B
  __shared__ float4 wpk[CIN][2];  // [c][0]=w3, [c][1]=w1next^T 8192 B
  __shared__ float4 b3s[64];      //                            1024 B
  __shared__ float h2A[4][112];   // step-A conv out, 10x10     1792 B
  __shared__ float4 h1n[12][13];  // h1_{k+1} region 10x10      2496 B
  __shared__ float h2Bs[4][64];   // step-B conv out            1024 B
  __shared__ float4 comb[8][117]; // expand partials           14976 B

  int tid = threadIdx.x;
  int lane = tid & 63;
  int wvu = __builtin_amdgcn_readfirstlane(tid >> 6); // conv oc
  int q = tid >> 5, pg = tid & 31;                    // expand split
  int x0 = blockIdx.x * 8, y0 = blockIdx.y * 8, n = blockIdx.z;
  int lx = lane & 7, ly = lane >> 3;

  // ---- P0: stage h1 tile (zero halo) + step-A weights ----
  if (tid < 144) {
    int cy = tid / 12, cx = tid % 12;
    int sy = y0 - 2 + cy, sx = x0 - 2 + cx;
    float4 v = make_float4(0.f, 0.f, 0.f, 0.f);
    if (sy >= 0 && sy < HH && sx >= 0 && sx < WW)
      v = *(const float4*)&h1in[((n * HH + sy) * WW + sx) * CB];
    h1t[cy][cx] = v;
  }
  {
    int c = tid;
    wpk[c][0] = *(const float4*)&w3A[c * 4];
    float4 wt;
    wt.x = w1A[c]; wt.y = w1A[256 + c];
    wt.z = w1A[512 + c]; wt.w = w1A[768 + c];
    wpk[c][1] = wt;
    if (tid < 64) b3s[tid] = *(const float4*)&b3A[tid * 4];
  }
  __syncthreads(); // S0

  // ---- P1: conv A on 10x10 region (oc = wave, <=2 px per lane) ----
  {
    const float* w2w = w2A + wvu * 36; // uniform -> s_load
#pragma unroll
    for (int rep = 0; rep < 2; ++rep) {
      int p = lane + rep * 64;
      if (p < 100) {
        int ay = p / 10, ax = p % 10;
        float a0 = b2A[wvu], a1 = 0.f, a2 = 0.f;
#pragma unroll
        for (int dy = 0; dy < 3; ++dy) {
          float4 va = h1t[ay + dy][ax];
          float4 vb = h1t[ay + dy][ax + 1];
          float4 vc = h1t[ay + dy][ax + 2];
          int pp = dy * 3;
          a0 = fmaf(va.x, w2w[pp], a0);
          a0 = fmaf(va.y, w2w[9 + pp], a0);
          a0 = fmaf(va.z, w2w[18 + pp], a0);
          a0 = fmaf(va.w, w2w[27 + pp], a0);
          a1 = fmaf(vb.x, w2w[pp + 1], a1);
          a1 = fmaf(vb.y, w2w[9 + pp + 1], a1);
          a1 = fmaf(vb.z, w2w[18 + pp + 1], a1);
          a1 = fmaf(vb.w, w2w[27 + pp + 1], a1);
          a2 = fmaf(vc.x, w2w[pp + 2], a2);
          a2 = fmaf(vc.y, w2w[9 + pp + 2], a2);
          a2 = fmaf(vc.z, w2w[18 + pp + 2], a2);
          a2 = fmaf(vc.w, w2w[27 + pp + 2], a2);
        }
        h2A[wvu][p] = fmaxf(a0 + a1 + a2, 0.f);
      }
    }
  }
  __syncthreads(); // S1

  // ---- P2: expand A (32ch x 4px per thread) + h2A interior store ----
  {
    float4 h2r[4], tp[4];
#pragma unroll
    for (int j = 0; j < 4; ++j) {
      int p = pg * 4 + j;
      int pc = (p < 100) ? p : 99;
      h2r[j].x = h2A[0][pc]; h2r[j].y = h2A[1][pc];
      h2r[j].z = h2A[2][pc]; h2r[j].w = h2A[3][pc];
      tp[j] = make_float4(0.f, 0.f, 0.f, 0.f);
    }
#pragma unroll
    for (int cc = 0; cc < 32; ++cc) {
      int c = q * 32 + cc;
      float4 w3v = wpk[c][0]; // 2-addr broadcast per wave
      float4 wnv = wpk[c][1];
      float bb = ((const float*)b3s)[c];
#pragma unroll
      for (int j = 0; j < 4; ++j) {
        float u = fmaf(h2r[j].x, w3v.x, bb);
        u = fmaf(h2r[j].y, w3v.y, u);
        u = fmaf(h2r[j].z, w3v.z, u);
        u = fmaf(h2r[j].w, w3v.w, u);
        float v = fmaxf(u, 0.f);
        tp[j].x = fmaf(v, wnv.x, tp[j].x);
        tp[j].y = fmaf(v, wnv.y, tp[j].y);
        tp[j].z = fmaf(v, wnv.z, tp[j].z);
        tp[j].w = fmaf(v, wnv.w, tp[j].w);
      }
    }
#pragma unroll
    for (int j = 0; j < 4; ++j) {
      int p = pg * 4 + j;
      if (p < 100) comb[q][swzp(p)] = tp[j];
    }
    if (tid < 64) { // gather interior h2A -> global (phaseC input, step kA)
      int p = (ly + 1) * 10 + lx + 1;
      float4 h;
      h.x = h2A[0][p]; h.y = h2A[1][p]; h.z = h2A[2][p]; h.w = h2A[3][p];
      *(float4*)&h2outA[((n * HH + y0 + ly) * WW + x0 + lx) * CB] = h;
    }
  }
  __syncthreads(); // S2

  // ---- P3: reduce A -> h1n (10x10, zero outside image) + stage B wts ----
  if (tid < 100) {
    int m = swzp(tid);
    float4 t = comb[0][m];
#pragma unroll
    for (int qq = 1; qq < 8; ++qq) {
      float4 pv = comb[qq][m];
      t.x += pv.x; t.y += pv.y; t.z += pv.z; t.w += pv.w;
    }
    int ay = tid / 10, ax = tid % 10;
    int gy = y0 - 1 + ay, gx = x0 - 1 + ax;
    float4 r;
    r.x = fmaxf(t.x + b1A[0], 0.f);
    r.y = fmaxf(t.y + b1A[1], 0.f);
    r.z = fmaxf(t.z + b1A[2], 0.f);
    r.w = fmaxf(t.w + b1A[3], 0.f);
    if (gy < 0 || gy >= HH || gx < 0 || gx >= WW)
      r = make_float4(0.f, 0.f, 0.f, 0.f); // exact SAME-pad for step B
    h1n[ay][ax] = r;
  }
  {
    int c = tid;
    wpk[c][0] = *(const float4*)&w3B[c * 4];
    float4 wt;
    wt.x = w1B[c]; wt.y = w1B[256 + c];
    wt.z = w1B[512 + c]; wt.w = w1B[768 + c];
    wpk[c][1] = wt;
    if (tid < 64) b3s[tid] = *(const float4*)&b3B[tid * 4];
  }
  __syncthreads(); // S3

  // ---- P4: conv B on 8x8 tile (oc = wave, 1 px per lane) ----
  {
    const float* w2w = w2B + wvu * 36; // uniform -> s_load
    float a0 = b2B[wvu], a1 = 0.f, a2 = 0.f;
#pragma unroll
    for (int dy = 0; dy < 3; ++dy) {
      float4 va = h1n[ly + dy][lx];
      float4 vb = h1n[ly + dy][lx + 1];
      float4 vc = h1n[ly + dy][lx + 2];
      int pp = dy * 3;
      a0 = fmaf(va.x, w2w[pp], a0);
      a0 = fmaf(va.y, w2w[9 + pp], a0);
      a0 = fmaf(va.z, w2w[18 + pp], a0);
      a0 = fmaf(va.w, w2w[27 + pp], a0);
      a1 = fmaf(vb.x, w2w[pp + 1], a1);
      a1 = fmaf(vb.y, w2w[9 + pp + 1], a1);
      a1 = fmaf(vb.z, w2w[18 + pp + 1], a1);
      a1 = fmaf(vb.w, w2w[27 + pp + 1], a1);
      a2 = fmaf(vc.x, w2w[pp + 2], a2);
      a2 = fmaf(vc.y, w2w[9 + pp + 2], a2);
      a2 = fmaf(vc.z, w2w[18 + pp + 2], a2);
      a2 = fmaf(vc.w, w2w[27 + pp + 2], a2);
    }
    h2Bs[wvu][lane] = fmaxf(a0 + a1 + a2, 0.f);
  }
  __syncthreads(); // S4

  // ---- P5: h2B store + expand B (32ch x 2px per thread) ----
  if (tid < 64) {
    float4 h;
    h.x = h2Bs[0][lane]; h.y = h2Bs[1][lane];
    h.z = h2Bs[2][lane]; h.w = h2Bs[3][lane];
    *(float4*)&h2outB[((n * HH + y0 + ly) * WW + x0 + lx) * CB] = h;
  }
  if (compute_next) {
    float4 hb[2], tp[2];
#pragma unroll
    for (int j = 0; j < 2; ++j) {
      int p = pg * 2 + j;
      hb[j].x = h2Bs[0][p]; hb[j].y = h2Bs[1][p];
      hb[j].z = h2Bs[2][p]; hb[j].w = h2Bs[3][p];
      tp[j] = make_float4(0.f, 0.f, 0.f, 0.f);
    }
#pragma unroll
    for (int cc = 0; cc < 32; ++cc) {
      int c = q * 32 + cc;
      float4 w3v = wpk[c][0];
      float4 wnv = wpk[c][1];
      float bb = ((const float*)b3s)[c];
#pragma unroll
      for (int j = 0; j < 2; ++j) {
        float u = fmaf(hb[j].x, w3v.x, bb);
        u = fmaf(hb[j].y, w3v.y, u);
        u = fmaf(hb[j].z, w3v.z, u);
        u = fmaf(hb[j].w, w3v.w, u);
        float v = fmaxf(u, 0.f);
        tp[j].x = fmaf(v, wnv.x, tp[j].x);
        tp[j].y = fmaf(v, wnv.y, tp[j].y);
        tp[j].z = fmaf(v, wnv.z, tp[j].z);
        tp[j].w = fmaf(v, wnv.w, tp[j].w);
      }
    }
#pragma unroll
    for (int j = 0; j < 2; ++j) comb[q][swzp(pg * 2 + j)] = tp[j];
  }
  __syncthreads(); // S5

  if (compute_next && tid < 64) {
    int m = swzp(lane);
    float4 t = comb[0][m];
#pragma unroll
    for (int qq = 1; qq < 8; ++qq) {
      float4 pv = comb[qq][m];
      t.x += pv.x; t.y += pv.y; t.z += pv.z; t.w += pv.w;
    }
    float4 r;
    r.x = fmaxf(t.x + b1B[0], 0.f);
    r.y = fmaxf(t.y + b1B[1], 0.f);
    r.z = fmaxf(t.z + b1B[2], 0.f);
    r.w = fmaxf(t.w + b1B[3], 0.f);
    *(float4*)&h1out[((n * HH + y0 + ly) * WW + x0 + lx) * CB] = r;
  }
}

// ---------------- Phase C: acc = sum_k relu(W3_k h2_k + b3_k) ------------
// R0 version VERBATIM (measured 100.5us, VGPR 52 < 64-cap, 0 conflicts).
// Lane = channel: tid = c, block covers PXT=32 consecutive pixels. Weights
// in registers (coalesced per-k loads), h2 broadcast from double-buffered
// LDS. Padded LDS transpose for coalesced stores. grid (128, 16).
__global__ __launch_bounds__(256, 4) void phaseC(
    const float* __restrict__ h2buf, const float* __restrict__ w3g,
    const float* __restrict__ b3g, float* __restrict__ out) {
  __shared__ float4 h2s[2][PXT];
  __shared__ float tr[CIN][PXT + 1]; // +1 pad: 2-way bank alias = free
  int tid = threadIdx.x;             // channel c
  int p0 = blockIdx.x * PXT;         // flat pixel y*64+x
  int n = blockIdx.y;
  float acc[PXT];
#pragma unroll
  for (int i = 0; i < PXT; ++i) acc[i] = 0.f;

  if (tid < PXT)
    h2s[0][tid] = *(const float4*)&h2buf[((0 * NN + n) * 4096 + p0 + tid) * 4];
  __syncthreads();

  for (int k = 0; k < NBLK; ++k) {
    float4 wv = *(const float4*)&w3g[(k * 256 + tid) * 4]; // coalesced
    float bv = b3g[k * 256 + tid];
    if (k + 1 < NBLK && tid < PXT)
      h2s[(k + 1) & 1][tid] =
          *(const float4*)&h2buf[(((k + 1) * NN + n) * 4096 + p0 + tid) * 4];
    const float4* hb = h2s[k & 1];
#pragma unroll
    for (int i = 0; i < PXT; ++i) {
      float4 h = hb[i]; // broadcast ds_read_b128
      float u = fmaf(h.w, wv.w,
                fmaf(h.z, wv.z, fmaf(h.y, wv.y, fmaf(h.x, wv.x, bv))));
      acc[i] += fmaxf(u, 0.f);
    }
    __syncthreads();
  }

  // transpose in LDS -> coalesced stores
#pragma unroll
  for (int i = 0; i < PXT; ++i) tr[tid][i] = acc[i];
  __syncthreads();
  int xi = tid & 31, cb = tid >> 5; // 8 channel-groups per pass
#pragma unroll
  for (int j = 0; j < 32; ++j) {
    int c = cb + j * 8;
    out[(n * CIN + c) * (HH * WW) + p0 + xi] = tr[c][xi];
  }
}

extern "C" void kernel_launch(void* const* d_in, const int* in_sizes, int n_in,
                              void* d_out, int out_size, void* d_ws, size_t ws_size,
                              hipStream_t stream) {
  const float* x  = (const float*)d_in[0];
  const float* w1 = (const float*)d_in[1]; // [32][4][256]
  const float* b1 = (const float*)d_in[2]; // [32][4]
  const float* w2 = (const float*)d_in[3]; // [32][4][4][3][3]
  const float* b2 = (const float*)d_in[4]; // [32][4]
  const float* w3 = (const float*)d_in[5]; // [32][256][4]
  const float* b3 = (const float*)d_in[6]; // [32][256]
  float* out = (float*)d_out;
  float* ws = (float*)d_ws;

  const int STATE = NN * HH * WW * CB; // 262144 floats = 1 MiB
  float* h1a = ws;
  float* h1b = ws + STATE;
  float* h2  = ws + 2 * STATE; // 32 MiB -> total 34 MiB (proven footprint)

  phaseA<<<dim3(HH, NN), 256, 0, stream>>>(x, w1, b1, h1a);
  for (int t = 0; t < NBLK / 2; ++t) {
    int kA = 2 * t, kB = 2 * t + 1;
    const float* hin = (t & 1) ? h1b : h1a;
    float* hout = (t & 1) ? h1a : h1b;
    int knA = kA + 1;                       // always <= 31
    int knB = (kB + 1 < NBLK) ? kB + 1 : NBLK - 1; // clamped, unused on last
    phaseB2<<<dim3(8, 8, NN), 256, 0, stream>>>(
        hin, hout, h2 + kA * STATE, h2 + kB * STATE,
        w2 + kA * 144, b2 + kA * CB, w3 + kA * 1024, b3 + kA * 256,
        w1 + knA * 1024, b1 + knA * CB,
        w2 + kB * 144, b2 + kB * CB, w3 + kB * 1024, b3 + kB * 256,
        w1 + knB * 1024, b1 + knB * CB,
        (t < NBLK / 2 - 1) ? 1 : 0);
  }
  phaseC<<<dim3((HH * WW) / PXT, NN), 256, 0, stream>>>(h2, w3, b3, out);
}

// Round 8
// 458.470 us; speedup vs baseline: 9.6098x; 3.0597x over previous
//
#include <hip/hip_runtime.h>

// 32 chained bottleneck blocks on x[16,256,64,64] fp32.
// Phase A: h1_0 = relu(W1_0 x + b1_0)           (reads x once)
// Phase B2 (x16): TWO fused bottleneck steps per dispatch via halo
//   recompute: stage h1 12x12 (2-halo), step A on 10x10, step B on 8x8.
// Phase C: out = sum_k relu(W3_k h2_k + b3_k)   (R0 version, 100us proven)
//
// R14: R7's phaseB2 ~80us/dispatch was RESIDUAL spill: full unroll of the
// 32-deep expand loops lets the scheduler hoist ~64 ds_read_b128 results
// -> live set > 128 cap. Fix: #pragma unroll 4 on expand/reduce loops
// (bounds in-flight weights to 32 VGPR). R6(64-cap)=289us, R7(128-cap)=80us,
// R14(128-cap+unroll4) predicted ~16us. Everything else identical to R7
// (passed twice).

#define NN 16
#define HH 64
#define WW 64
#define CIN 256
#define CB 4
#define NBLK 32
#define PXT 32  // pixels per phaseC block

// bijective swizzle: spreads stride-4/2 f4 patterns across banks
__device__ __forceinline__ int swzp(int p) { return p ^ ((p >> 3) & 7); }

// ---------------- Phase A: h1_0 = relu(W1_0 . x + b1_0) ------------------
__global__ __launch_bounds__(256) void phaseA(
    const float* __restrict__ x, const float* __restrict__ w1,
    const float* __restrict__ b1, float* __restrict__ h1out) {
  __shared__ float4 w1s[CIN];
  __shared__ float4 part[4][WW];
  int tid = threadIdx.x;
  for (int i = tid; i < CIN * CB; i += 256) {
    int o = i >> 8, c = i & 255;
    ((float*)&w1s[c])[o] = w1[i]; // w1 global layout [o][c]
  }
  __syncthreads();
  int y = blockIdx.x, n = blockIdx.y;
  int chunk = tid >> 6, px = tid & 63;
  int cbase = chunk * 64;
  const float* xp = x + ((n * CIN + cbase) * HH + y) * WW + px;
  float s0 = 0.f, s1 = 0.f, s2 = 0.f, s3 = 0.f;
#pragma unroll 8
  for (int i = 0; i < 64; ++i) {
    float xv = xp[i * HH * WW];
    float4 wv = w1s[cbase + i];
    s0 = fmaf(xv, wv.x, s0);
    s1 = fmaf(xv, wv.y, s1);
    s2 = fmaf(xv, wv.z, s2);
    s3 = fmaf(xv, wv.w, s3);
  }
  part[chunk][px] = make_float4(s0, s1, s2, s3);
  __syncthreads();
  int px2 = tid >> 2, o = tid & 3;
  float v = ((float*)&part[0][px2])[o] + ((float*)&part[1][px2])[o] +
            ((float*)&part[2][px2])[o] + ((float*)&part[3][px2])[o];
  v += b1[o];
  h1out[((n * HH + y) * WW + px2) * CB + o] = fmaxf(v, 0.f);
}

// ---------------- Phase B2: two fused bottleneck steps -------------------
// 8x8 output tile, 256 threads, grid (8,8,16) = 1024 blocks.
// Step A on the 10x10 halo region (recompute), step B on the 8x8 tile.
// Expand: q = tid>>5 owns 32 channels (weight reads 2-addr broadcast),
// pg = tid&31 owns 4 px (A) / 2 px (B). 6 barriers per dispatch.
// (256,2): 128-VGPR cap; unroll-4 keeps live set ~100 -> no spill.
__global__ __launch_bounds__(256, 2) void phaseB2(
    const float* __restrict__ h1in, float* __restrict__ h1out,
    float* __restrict__ h2outA, float* __restrict__ h2outB,
    const float* __restrict__ w2A, const float* __restrict__ b2A,
    const float* __restrict__ w3A, const float* __restrict__ b3A,
    const float* __restrict__ w1A, const float* __restrict__ b1A, // k+1
    const float* __restrict__ w2B, const float* __restrict__ b2B,
    const float* __restrict__ w3B, const float* __restrict__ b3B,
    const float* __restrict__ w1B, const float* __restrict__ b1B, // k+2
    int compute_next) {
  __shared__ float4 h1t[12][13];  // staged h1, 2-halo          2496 B
  __shared__ float4 wpk[CIN][2];  // [c][0]=w3, [c][1]=w1next^T 8192 B
  __shared__ float4 b3s[64];      //                            1024 B
  __shared__ float h2A[4][112];   // step-A conv out, 10x10     1792 B
  __shared__ float4 h1n[12][13];  // h1_{k+1} region 10x10      2496 B
  __shared__ float h2Bs[4][64];   // step-B conv out            1024 B
  __shared__ float4 comb[8][117]; // expand partials           14976 B

  int tid = threadIdx.x;
  int lane = tid & 63;
  int wvu = __builtin_amdgcn_readfirstlane(tid >> 6); // conv oc
  int q = tid >> 5, pg = tid & 31;                    // expand split
  int x0 = blockIdx.x * 8, y0 = blockIdx.y * 8, n = blockIdx.z;
  int lx = lane & 7, ly = lane >> 3;

  // ---- P0: stage h1 tile (zero halo) + step-A weights ----
  if (tid < 144) {
    int cy = tid / 12, cx = tid % 12;
    int sy = y0 - 2 + cy, sx = x0 - 2 + cx;
    float4 v = make_float4(0.f, 0.f, 0.f, 0.f);
    if (sy >= 0 && sy < HH && sx >= 0 && sx < WW)
      v = *(const float4*)&h1in[((n * HH + sy) * WW + sx) * CB];
    h1t[cy][cx] = v;
  }
  {
    int c = tid;
    wpk[c][0] = *(const float4*)&w3A[c * 4];
    float4 wt;
    wt.x = w1A[c]; wt.y = w1A[256 + c];
    wt.z = w1A[512 + c]; wt.w = w1A[768 + c];
    wpk[c][1] = wt;
    if (tid < 64) b3s[tid] = *(const float4*)&b3A[tid * 4];
  }
  __syncthreads(); // S0

  // ---- P1: conv A on 10x10 region (oc = wave, <=2 px per lane) ----
  {
    const float* w2w = w2A + wvu * 36; // uniform -> s_load
#pragma unroll
    for (int rep = 0; rep < 2; ++rep) {
      int p = lane + rep * 64;
      if (p < 100) {
        int ay = p / 10, ax = p % 10;
        float a0 = b2A[wvu], a1 = 0.f, a2 = 0.f;
#pragma unroll
        for (int dy = 0; dy < 3; ++dy) {
          float4 va = h1t[ay + dy][ax];
          float4 vb = h1t[ay + dy][ax + 1];
          float4 vc = h1t[ay + dy][ax + 2];
          int pp = dy * 3;
          a0 = fmaf(va.x, w2w[pp], a0);
          a0 = fmaf(va.y, w2w[9 + pp], a0);
          a0 = fmaf(va.z, w2w[18 + pp], a0);
          a0 = fmaf(va.w, w2w[27 + pp], a0);
          a1 = fmaf(vb.x, w2w[pp + 1], a1);
          a1 = fmaf(vb.y, w2w[9 + pp + 1], a1);
          a1 = fmaf(vb.z, w2w[18 + pp + 1], a1);
          a1 = fmaf(vb.w, w2w[27 + pp + 1], a1);
          a2 = fmaf(vc.x, w2w[pp + 2], a2);
          a2 = fmaf(vc.y, w2w[9 + pp + 2], a2);
          a2 = fmaf(vc.z, w2w[18 + pp + 2], a2);
          a2 = fmaf(vc.w, w2w[27 + pp + 2], a2);
        }
        h2A[wvu][p] = fmaxf(a0 + a1 + a2, 0.f);
      }
    }
  }
  __syncthreads(); // S1

  // ---- P2: expand A (32ch x 4px per thread) + h2A interior store ----
  {
    float4 h2r[4], tp[4];
#pragma unroll
    for (int j = 0; j < 4; ++j) {
      int p = pg * 4 + j;
      int pc = (p < 100) ? p : 99;
      h2r[j].x = h2A[0][pc]; h2r[j].y = h2A[1][pc];
      h2r[j].z = h2A[2][pc]; h2r[j].w = h2A[3][pc];
      tp[j] = make_float4(0.f, 0.f, 0.f, 0.f);
    }
#pragma unroll 4  // bound hoisted ds_read results: ~8 f4 in flight max
    for (int cc = 0; cc < 32; ++cc) {
      int c = q * 32 + cc;
      float4 w3v = wpk[c][0]; // 2-addr broadcast per wave
      float4 wnv = wpk[c][1];
      float bb = ((const float*)b3s)[c];
#pragma unroll
      for (int j = 0; j < 4; ++j) {
        float u = fmaf(h2r[j].x, w3v.x, bb);
        u = fmaf(h2r[j].y, w3v.y, u);
        u = fmaf(h2r[j].z, w3v.z, u);
        u = fmaf(h2r[j].w, w3v.w, u);
        float v = fmaxf(u, 0.f);
        tp[j].x = fmaf(v, wnv.x, tp[j].x);
        tp[j].y = fmaf(v, wnv.y, tp[j].y);
        tp[j].z = fmaf(v, wnv.z, tp[j].z);
        tp[j].w = fmaf(v, wnv.w, tp[j].w);
      }
    }
#pragma unroll
    for (int j = 0; j < 4; ++j) {
      int p = pg * 4 + j;
      if (p < 100) comb[q][swzp(p)] = tp[j];
    }
    if (tid < 64) { // gather interior h2A -> global (phaseC input, step kA)
      int p = (ly + 1) * 10 + lx + 1;
      float4 h;
      h.x = h2A[0][p]; h.y = h2A[1][p]; h.z = h2A[2][p]; h.w = h2A[3][p];
      *(float4*)&h2outA[((n * HH + y0 + ly) * WW + x0 + lx) * CB] = h;
    }
  }
  __syncthreads(); // S2

  // ---- P3: reduce A -> h1n (10x10, zero outside image) + stage B wts ----
  if (tid < 100) {
    int m = swzp(tid);
    float4 t = comb[0][m];
#pragma unroll 4  // limit hoisted comb reads
    for (int qq = 1; qq < 8; ++qq) {
      float4 pv = comb[qq][m];
      t.x += pv.x; t.y += pv.y; t.z += pv.z; t.w += pv.w;
    }
    int ay = tid / 10, ax = tid % 10;
    int gy = y0 - 1 + ay, gx = x0 - 1 + ax;
    float4 r;
    r.x = fmaxf(t.x + b1A[0], 0.f);
    r.y = fmaxf(t.y + b1A[1], 0.f);
    r.z = fmaxf(t.z + b1A[2], 0.f);
    r.w = fmaxf(t.w + b1A[3], 0.f);
    if (gy < 0 || gy >= HH || gx < 0 || gx >= WW)
      r = make_float4(0.f, 0.f, 0.f, 0.f); // exact SAME-pad for step B
    h1n[ay][ax] = r;
  }
  {
    int c = tid;
    wpk[c][0] = *(const float4*)&w3B[c * 4];
    float4 wt;
    wt.x = w1B[c]; wt.y = w1B[256 + c];
    wt.z = w1B[512 + c]; wt.w = w1B[768 + c];
    wpk[c][1] = wt;
    if (tid < 64) b3s[tid] = *(const float4*)&b3B[tid * 4];
  }
  __syncthreads(); // S3

  // ---- P4: conv B on 8x8 tile (oc = wave, 1 px per lane) ----
  {
    const float* w2w = w2B + wvu * 36; // uniform -> s_load
    float a0 = b2B[wvu], a1 = 0.f, a2 = 0.f;
#pragma unroll
    for (int dy = 0; dy < 3; ++dy) {
      float4 va = h1n[ly + dy][lx];
      float4 vb = h1n[ly + dy][lx + 1];
      float4 vc = h1n[ly + dy][lx + 2];
      int pp = dy * 3;
      a0 = fmaf(va.x, w2w[pp], a0);
      a0 = fmaf(va.y, w2w[9 + pp], a0);
      a0 = fmaf(va.z, w2w[18 + pp], a0);
      a0 = fmaf(va.w, w2w[27 + pp], a0);
      a1 = fmaf(vb.x, w2w[pp + 1], a1);
      a1 = fmaf(vb.y, w2w[9 + pp + 1], a1);
      a1 = fmaf(vb.z, w2w[18 + pp + 1], a1);
      a1 = fmaf(vb.w, w2w[27 + pp + 1], a1);
      a2 = fmaf(vc.x, w2w[pp + 2], a2);
      a2 = fmaf(vc.y, w2w[9 + pp + 2], a2);
      a2 = fmaf(vc.z, w2w[18 + pp + 2], a2);
      a2 = fmaf(vc.w, w2w[27 + pp + 2], a2);
    }
    h2Bs[wvu][lane] = fmaxf(a0 + a1 + a2, 0.f);
  }
  __syncthreads(); // S4

  // ---- P5: h2B store + expand B (32ch x 2px per thread) ----
  if (tid < 64) {
    float4 h;
    h.x = h2Bs[0][lane]; h.y = h2Bs[1][lane];
    h.z = h2Bs[2][lane]; h.w = h2Bs[3][lane];
    *(float4*)&h2outB[((n * HH + y0 + ly) * WW + x0 + lx) * CB] = h;
  }
  if (compute_next) {
    float4 hb[2], tp[2];
#pragma unroll
    for (int j = 0; j < 2; ++j) {
      int p = pg * 2 + j;
      hb[j].x = h2Bs[0][p]; hb[j].y = h2Bs[1][p];
      hb[j].z = h2Bs[2][p]; hb[j].w = h2Bs[3][p];
      tp[j] = make_float4(0.f, 0.f, 0.f, 0.f);
    }
#pragma unroll 4  // bound hoisted ds_read results
    for (int cc = 0; cc < 32; ++cc) {
      int c = q * 32 + cc;
      float4 w3v = wpk[c][0];
      float4 wnv = wpk[c][1];
      float bb = ((const float*)b3s)[c];
#pragma unroll
      for (int j = 0; j < 2; ++j) {
        float u = fmaf(hb[j].x, w3v.x, bb);
        u = fmaf(hb[j].y, w3v.y, u);
        u = fmaf(hb[j].z, w3v.z, u);
        u = fmaf(hb[j].w, w3v.w, u);
        float v = fmaxf(u, 0.f);
        tp[j].x = fmaf(v, wnv.x, tp[j].x);
        tp[j].y = fmaf(v, wnv.y, tp[j].y);
        tp[j].z = fmaf(v, wnv.z, tp[j].z);
        tp[j].w = fmaf(v, wnv.w, tp[j].w);
      }
    }
#pragma unroll
    for (int j = 0; j < 2; ++j) comb[q][swzp(pg * 2 + j)] = tp[j];
  }
  __syncthreads(); // S5

  if (compute_next && tid < 64) {
    int m = swzp(lane);
    float4 t = comb[0][m];
#pragma unroll 4  // limit hoisted comb reads
    for (int qq = 1; qq < 8; ++qq) {
      float4 pv = comb[qq][m];
      t.x += pv.x; t.y += pv.y; t.z += pv.z; t.w += pv.w;
    }
    float4 r;
    r.x = fmaxf(t.x + b1B[0], 0.f);
    r.y = fmaxf(t.y + b1B[1], 0.f);
    r.z = fmaxf(t.z + b1B[2], 0.f);
    r.w = fmaxf(t.w + b1B[3], 0.f);
    *(float4*)&h1out[((n * HH + y0 + ly) * WW + x0 + lx) * CB] = r;
  }
}

// ---------------- Phase C: acc = sum_k relu(W3_k h2_k + b3_k) ------------
// R0 version VERBATIM (measured 99-100us, VGPR 52 < 64-cap, 0 conflicts).
__global__ __launch_bounds__(256, 4) void phaseC(
    const float* __restrict__ h2buf, const float* __restrict__ w3g,
    const float* __restrict__ b3g, float* __restrict__ out) {
  __shared__ float4 h2s[2][PXT];
  __shared__ float tr[CIN][PXT + 1]; // +1 pad: 2-way bank alias = free
  int tid = threadIdx.x;             // channel c
  int p0 = blockIdx.x * PXT;         // flat pixel y*64+x
  int n = blockIdx.y;
  float acc[PXT];
#pragma unroll
  for (int i = 0; i < PXT; ++i) acc[i] = 0.f;

  if (tid < PXT)
    h2s[0][tid] = *(const float4*)&h2buf[((0 * NN + n) * 4096 + p0 + tid) * 4];
  __syncthreads();

  for (int k = 0; k < NBLK; ++k) {
    float4 wv = *(const float4*)&w3g[(k * 256 + tid) * 4]; // coalesced
    float bv = b3g[k * 256 + tid];
    if (k + 1 < NBLK && tid < PXT)
      h2s[(k + 1) & 1][tid] =
          *(const float4*)&h2buf[(((k + 1) * NN + n) * 4096 + p0 + tid) * 4];
    const float4* hb = h2s[k & 1];
#pragma unroll
    for (int i = 0; i < PXT; ++i) {
      float4 h = hb[i]; // broadcast ds_read_b128
      float u = fmaf(h.w, wv.w,
                fmaf(h.z, wv.z, fmaf(h.y, wv.y, fmaf(h.x, wv.x, bv))));
      acc[i] += fmaxf(u, 0.f);
    }
    __syncthreads();
  }

  // transpose in LDS -> coalesced stores
#pragma unroll
  for (int i = 0; i < PXT; ++i) tr[tid][i] = acc[i];
  __syncthreads();
  int xi = tid & 31, cb = tid >> 5; // 8 channel-groups per pass
#pragma unroll
  for (int j = 0; j < 32; ++j) {
    int c = cb + j * 8;
    out[(n * CIN + c) * (HH * WW) + p0 + xi] = tr[c][xi];
  }
}

extern "C" void kernel_launch(void* const* d_in, const int* in_sizes, int n_in,
                              void* d_out, int out_size, void* d_ws, size_t ws_size,
                              hipStream_t stream) {
  const float* x  = (const float*)d_in[0];
  const float* w1 = (const float*)d_in[1]; // [32][4][256]
  const float* b1 = (const float*)d_in[2]; // [32][4]
  const float* w2 = (const float*)d_in[3]; // [32][4][4][3][3]
  const float* b2 = (const float*)d_in[4]; // [32][4]
  const float* w3 = (const float*)d_in[5]; // [32][256][4]
  const float* b3 = (const float*)d_in[6]; // [32][256]
  float* out = (float*)d_out;
  float* ws = (float*)d_ws;

  const int STATE = NN * HH * WW * CB; // 262144 floats = 1 MiB
  float* h1a = ws;
  float* h1b = ws + STATE;
  float* h2  = ws + 2 * STATE; // 32 MiB -> total 34 MiB (proven footprint)

  phaseA<<<dim3(HH, NN), 256, 0, stream>>>(x, w1, b1, h1a);
  for (int t = 0; t < NBLK / 2; ++t) {
    int kA = 2 * t, kB = 2 * t + 1;
    const float* hin = (t & 1) ? h1b : h1a;
    float* hout = (t & 1) ? h1a : h1b;
    int knA = kA + 1;                       // always <= 31
    int knB = (kB + 1 < NBLK) ? kB + 1 : NBLK - 1; // clamped, unused on last
    phaseB2<<<dim3(8, 8, NN), 256, 0, stream>>>(
        hin, hout, h2 + kA * STATE, h2 + kB * STATE,
        w2 + kA * 144, b2 + kA * CB, w3 + kA * 1024, b3 + kA * 256,
        w1 + knA * 1024, b1 + knA * CB,
        w2 + kB * 144, b2 + kB * CB, w3 + kB * 1024, b3 + kB * 256,
        w1 + knB * 1024, b1 + knB * CB,
        (t < NBLK / 2 - 1) ? 1 : 0);
  }
  phaseC<<<dim3((HH * WW) / PXT, NN), 256, 0, stream>>>(h2, w3, b3, out);
}